// Round 1
// baseline (418.799 us; speedup 1.0000x reference)
//
#include <hip/hip_runtime.h>
#include <hip/hip_bf16.h>
#include <stdint.h>

// Problem constants
#define BB   4
#define SS   2048
#define DIN  1024
#define DOUT 1024
#define NH   16
#define HD   64
#define MROWS (BB * SS)   // 8192

typedef __bf16 bf16x8 __attribute__((ext_vector_type(8)));
typedef float  f32x4  __attribute__((ext_vector_type(4)));

__device__ __forceinline__ unsigned short f2bf(float f) {
  union { float f; uint32_t u; } v; v.f = f;
  uint32_t u = v.u;
  uint32_t r = (u + 0x7fffu + ((u >> 16) & 1u)) >> 16;
  return (unsigned short)r;
}

// ---------------- conversion kernels ----------------

__global__ void cvt_x_kernel(const float* __restrict__ in,
                             unsigned short* __restrict__ out, int n4) {
  int i = blockIdx.x * blockDim.x + threadIdx.x;
  int stride = gridDim.x * blockDim.x;
  for (; i < n4; i += stride) {
    float4 f = ((const float4*)in)[i];
    ushort4 o;
    o.x = f2bf(f.x); o.y = f2bf(f.y); o.z = f2bf(f.z); o.w = f2bf(f.w);
    ((ushort4*)out)[i] = o;
  }
}

// transpose-convert: out[n][k] = bf16(W[k][n]), per blockIdx.z matrix
__global__ void cvt_w_t_kernel(const float* __restrict__ w0,
                               const float* __restrict__ w1,
                               const float* __restrict__ w2,
                               const float* __restrict__ w3,
                               unsigned short* __restrict__ out) {
  __shared__ float tile[32][33];
  const float* src = (blockIdx.z == 0) ? w0 : (blockIdx.z == 1) ? w1
                   : (blockIdx.z == 2) ? w2 : w3;
  unsigned short* dst = out + (size_t)blockIdx.z * (DIN * DOUT);
  int kb = blockIdx.x * 32, nb = blockIdx.y * 32;
  tile[threadIdx.y][threadIdx.x] = src[(size_t)(kb + threadIdx.y) * DOUT + nb + threadIdx.x];
  __syncthreads();
  dst[(size_t)(nb + threadIdx.y) * DIN + kb + threadIdx.x] = f2bf(tile[threadIdx.x][threadIdx.y]);
}

// ---------------- GEMM core: 128x128 tile, 4 waves, bf16 MFMA ----------------
// A: row-major [.,1024] bf16 (pre-offset to tile row 0)
// BT: row-major [.,1024] bf16 = B transposed (pre-offset to tile col 0)
__device__ __forceinline__ void gemm_core(const unsigned short* __restrict__ A,
                                          const unsigned short* __restrict__ BT,
                                          f32x4 (&acc)[4][4]) {
  const int tid  = threadIdx.x;
  const int lane = tid & 63;
  const int wave = tid >> 6;
  const int wm = (wave >> 1) * 64, wn = (wave & 1) * 64;
  const int g = lane >> 4, c = lane & 15;
  const int r = tid >> 1, cs = (tid & 1) * 16;

  __shared__ __align__(16) unsigned short As[128][32];
  __shared__ __align__(16) unsigned short Bs[128][32];

  for (int mi = 0; mi < 4; mi++)
    for (int ni = 0; ni < 4; ni++)
      acc[mi][ni] = (f32x4){0.f, 0.f, 0.f, 0.f};

  for (int k0 = 0; k0 < 1024; k0 += 32) {
    const uint4* asrc = (const uint4*)(A + (size_t)r * 1024 + k0 + cs);
    const uint4* bsrc = (const uint4*)(BT + (size_t)r * 1024 + k0 + cs);
    uint4 av0 = asrc[0], av1 = asrc[1];
    uint4 bv0 = bsrc[0], bv1 = bsrc[1];
    __syncthreads();   // previous iteration's reads complete before overwrite
    *(uint4*)&As[r][cs]     = av0;
    *(uint4*)&As[r][cs + 8] = av1;
    *(uint4*)&Bs[r][cs]     = bv0;
    *(uint4*)&Bs[r][cs + 8] = bv1;
    __syncthreads();
    bf16x8 a[4], b[4];
#pragma unroll
    for (int mi = 0; mi < 4; mi++)
      a[mi] = *(const bf16x8*)&As[wm + mi * 16 + c][g * 8];
#pragma unroll
    for (int ni = 0; ni < 4; ni++)
      b[ni] = *(const bf16x8*)&Bs[wn + ni * 16 + c][g * 8];
#pragma unroll
    for (int mi = 0; mi < 4; mi++)
#pragma unroll
      for (int ni = 0; ni < 4; ni++)
        acc[mi][ni] = __builtin_amdgcn_mfma_f32_16x16x32_bf16(a[mi], b[ni], acc[mi][ni], 0, 0, 0);
  }
}

// QKV projection. z=0: Q (scaled 1/8) -> [b][h][s][hd]; z=1: K -> [b][h][s][hd];
// z=2: V -> transposed [b][h][hd][s]
__global__ __launch_bounds__(256) void gemm_qkv_kernel(
    const unsigned short* __restrict__ xb, const unsigned short* __restrict__ wt,
    unsigned short* __restrict__ qs, unsigned short* __restrict__ kbuf,
    unsigned short* __restrict__ vt) {
  const int nT = blockIdx.x, mT = blockIdx.y, z = blockIdx.z;
  f32x4 acc[4][4];
  gemm_core(xb + (size_t)mT * 128 * 1024,
            wt + (size_t)z * (DIN * DOUT) + (size_t)nT * 128 * 1024, acc);

  const int tid = threadIdx.x, lane = tid & 63, wave = tid >> 6;
  const int wm = (wave >> 1) * 64, wn = (wave & 1) * 64;
  const int g = lane >> 4, c = lane & 15;
  const float scale = (z == 0) ? 0.125f : 1.0f;
  unsigned short* dstQK = (z == 0) ? qs : kbuf;
#pragma unroll
  for (int mi = 0; mi < 4; mi++)
#pragma unroll
    for (int ni = 0; ni < 4; ni++) {
      int n = nT * 128 + wn + ni * 16 + c;
      int h = n >> 6, hd = n & 63;
#pragma unroll
      for (int jj = 0; jj < 4; jj++) {
        int m = mT * 128 + wm + mi * 16 + g * 4 + jj;
        int b = m >> 11, s = m & 2047;
        unsigned short val = f2bf(acc[mi][ni][jj] * scale);
        if (z < 2)
          dstQK[(((size_t)(b * NH + h)) * SS + s) * HD + hd] = val;
        else
          vt[(((size_t)(b * NH + h)) * HD + hd) * SS + s] = val;
      }
    }
}

// Output projection: out = ctx @ Wp + bp (fp32 out)
__global__ __launch_bounds__(256) void gemm_out_kernel(
    const unsigned short* __restrict__ ctx, const unsigned short* __restrict__ wtp,
    const float* __restrict__ bp, float* __restrict__ out) {
  const int nT = blockIdx.x, mT = blockIdx.y;
  f32x4 acc[4][4];
  gemm_core(ctx + (size_t)mT * 128 * 1024, wtp + (size_t)nT * 128 * 1024, acc);

  const int tid = threadIdx.x, lane = tid & 63, wave = tid >> 6;
  const int wm = (wave >> 1) * 64, wn = (wave & 1) * 64;
  const int g = lane >> 4, c = lane & 15;
#pragma unroll
  for (int mi = 0; mi < 4; mi++)
#pragma unroll
    for (int ni = 0; ni < 4; ni++) {
      int n = nT * 128 + wn + ni * 16 + c;
      float bias = bp[n];
#pragma unroll
      for (int jj = 0; jj < 4; jj++) {
        int m = mT * 128 + wm + mi * 16 + g * 4 + jj;
        out[(size_t)m * DOUT + n] = acc[mi][ni][jj] + bias;
      }
    }
}

// ---------------- flash attention ----------------
// grid: (S/64, H, B); block: 256 threads = 4 waves; each wave owns 16 q rows.
__global__ __launch_bounds__(256) void attn_kernel(
    const unsigned short* __restrict__ qs, const unsigned short* __restrict__ kbuf,
    const unsigned short* __restrict__ vt, unsigned short* __restrict__ ctx) {
  const int qt = blockIdx.x, h = blockIdx.y, b = blockIdx.z;
  const int tid = threadIdx.x, lane = tid & 63, w = tid >> 6;
  const int g = lane >> 4, c = lane & 15;
  const size_t bh = (size_t)(b * NH + h);
  const unsigned short* Q = qs + bh * SS * HD;
  const unsigned short* K = kbuf + bh * SS * HD;
  const unsigned short* V = vt + bh * HD * SS;   // [hd][s]
  const int q0 = qt * 64 + w * 16;

  bf16x8 aq[2];
  aq[0] = *(const bf16x8*)&Q[(size_t)(q0 + c) * HD + g * 8];
  aq[1] = *(const bf16x8*)&Q[(size_t)(q0 + c) * HD + 32 + g * 8];

  float m_run[4], l_run[4];
  f32x4 acc[4];
#pragma unroll
  for (int jj = 0; jj < 4; jj++) { m_run[jj] = -3.0e38f; l_run[jj] = 0.f; }
#pragma unroll
  for (int nh = 0; nh < 4; nh++) acc[nh] = (f32x4){0.f, 0.f, 0.f, 0.f};

  __shared__ __align__(16) unsigned short Klds[64][64];
  __shared__ __align__(16) unsigned short Vlds[64][64];   // [hd][kv]
  __shared__ __align__(16) unsigned short Plds[4][16][64];

  const int sr = tid >> 2, sc = (tid & 3) * 16;

  for (int kvt = 0; kvt <= qt; ++kvt) {
    const int kv0 = kvt * 64;
    uint4 k0v = *(const uint4*)&K[(size_t)(kv0 + sr) * HD + sc];
    uint4 k1v = *(const uint4*)&K[(size_t)(kv0 + sr) * HD + sc + 8];
    uint4 v0v = *(const uint4*)&V[(size_t)sr * SS + kv0 + sc];
    uint4 v1v = *(const uint4*)&V[(size_t)sr * SS + kv0 + sc + 8];
    __syncthreads();   // all waves done with previous tile's LDS
    *(uint4*)&Klds[sr][sc]     = k0v;
    *(uint4*)&Klds[sr][sc + 8] = k1v;
    *(uint4*)&Vlds[sr][sc]     = v0v;
    *(uint4*)&Vlds[sr][sc + 8] = v1v;
    __syncthreads();

    // S = Q K^T (q rows x 64 kv cols), 4 frags of 16x16
    f32x4 sv[4];
#pragma unroll
    for (int ni = 0; ni < 4; ni++) {
      sv[ni] = (f32x4){0.f, 0.f, 0.f, 0.f};
#pragma unroll
      for (int kk = 0; kk < 2; kk++) {
        bf16x8 kf = *(const bf16x8*)&Klds[ni * 16 + c][kk * 32 + g * 8];
        sv[ni] = __builtin_amdgcn_mfma_f32_16x16x32_bf16(aq[kk], kf, sv[ni], 0, 0, 0);
      }
    }
    if (kvt == qt) {  // causal mask, only the diagonal tile needs it
#pragma unroll
      for (int ni = 0; ni < 4; ni++)
#pragma unroll
        for (int jj = 0; jj < 4; jj++) {
          int kvg = kv0 + ni * 16 + c;
          int qg  = q0 + g * 4 + jj;
          if (kvg > qg) sv[ni][jj] = -3.0e38f;
        }
    }

    // online softmax per q row (row = (g, jj); 16 columns per frag live in 16 lanes)
    float p[4][4];
    float alpha[4];
#pragma unroll
    for (int jj = 0; jj < 4; jj++) {
      float mx = fmaxf(fmaxf(sv[0][jj], sv[1][jj]), fmaxf(sv[2][jj], sv[3][jj]));
#pragma unroll
      for (int d = 1; d < 16; d <<= 1) mx = fmaxf(mx, __shfl_xor(mx, d));
      float mnew = fmaxf(m_run[jj], mx);
      alpha[jj] = __expf(m_run[jj] - mnew);
      m_run[jj] = mnew;
      float rs = 0.f;
#pragma unroll
      for (int ni = 0; ni < 4; ni++) {
        float pv = __expf(sv[ni][jj] - mnew);
        p[ni][jj] = pv;
        rs += pv;
      }
#pragma unroll
      for (int d = 1; d < 16; d <<= 1) rs += __shfl_xor(rs, d);
      l_run[jj] = l_run[jj] * alpha[jj] + rs;
    }
#pragma unroll
    for (int nh = 0; nh < 4; nh++)
#pragma unroll
      for (int jj = 0; jj < 4; jj++) acc[nh][jj] *= alpha[jj];

    // transpose P through per-wave LDS into A-fragment layout
#pragma unroll
    for (int ni = 0; ni < 4; ni++)
#pragma unroll
      for (int jj = 0; jj < 4; jj++)
        Plds[w][g * 4 + jj][ni * 16 + c] = f2bf(p[ni][jj]);
    bf16x8 pa0 = *(const bf16x8*)&Plds[w][c][g * 8];
    bf16x8 pa1 = *(const bf16x8*)&Plds[w][c][32 + g * 8];

    // ctx += P V
#pragma unroll
    for (int nh = 0; nh < 4; nh++) {
      bf16x8 vb0 = *(const bf16x8*)&Vlds[nh * 16 + c][g * 8];
      bf16x8 vb1 = *(const bf16x8*)&Vlds[nh * 16 + c][32 + g * 8];
      acc[nh] = __builtin_amdgcn_mfma_f32_16x16x32_bf16(pa0, vb0, acc[nh], 0, 0, 0);
      acc[nh] = __builtin_amdgcn_mfma_f32_16x16x32_bf16(pa1, vb1, acc[nh], 0, 0, 0);
    }
  }

  // epilogue: ctx2d[b*S+s][h*64+hd] = acc / l
#pragma unroll
  for (int nh = 0; nh < 4; nh++)
#pragma unroll
    for (int jj = 0; jj < 4; jj++) {
      int m = q0 + g * 4 + jj;
      int col = h * HD + nh * 16 + c;
      size_t row = (size_t)b * SS + m;
      ctx[row * DOUT + col] = f2bf(acc[nh][jj] / l_run[jj]);
    }
}

// ---------------- launch ----------------

extern "C" void kernel_launch(void* const* d_in, const int* in_sizes, int n_in,
                              void* d_out, int out_size, void* d_ws, size_t ws_size,
                              hipStream_t stream) {
  const float* x  = (const float*)d_in[0];
  const float* Wq = (const float*)d_in[1];
  const float* Wk = (const float*)d_in[2];
  const float* Wv = (const float*)d_in[3];
  const float* Wp = (const float*)d_in[4];
  const float* bp = (const float*)d_in[5];
  float* out = (float*)d_out;

  unsigned short* ws = (unsigned short*)d_ws;
  unsigned short* xb = ws;                      // 8388608 elems (x bf16; later reused as ctx)
  unsigned short* wt = xb + (size_t)MROWS * DIN;       // 4 * 1048576 (Wq^T,Wk^T,Wv^T,Wp^T)
  unsigned short* qs = wt + (size_t)4 * DIN * DOUT;    // 8388608 (Q scaled, [b][h][s][hd])
  unsigned short* kb = qs + (size_t)MROWS * DOUT;      // 8388608 ([b][h][s][hd])
  unsigned short* vt = kb + (size_t)MROWS * DOUT;      // 8388608 ([b][h][hd][s])
  unsigned short* ctx = xb;                            // alias: x dead after projections

  cvt_x_kernel<<<4096, 256, 0, stream>>>(x, xb, (MROWS * DIN) / 4);
  cvt_w_t_kernel<<<dim3(32, 32, 4), dim3(32, 32), 0, stream>>>(Wq, Wk, Wv, Wp, wt);
  gemm_qkv_kernel<<<dim3(8, 64, 3), 256, 0, stream>>>(xb, wt, qs, kb, vt);
  attn_kernel<<<dim3(SS / 64, NH, BB), 256, 0, stream>>>(qs, kb, vt, ctx);
  gemm_out_kernel<<<dim3(8, 64), 256, 0, stream>>>(ctx, wt + (size_t)3 * DIN * DOUT, bp, out);
}

// Round 2
// 340.105 us; speedup vs baseline: 1.2314x; 1.2314x over previous
//
#include <hip/hip_runtime.h>
#include <hip/hip_bf16.h>
#include <stdint.h>

// Problem constants
#define BB   4
#define SS   2048
#define DIN  1024
#define DOUT 1024
#define NH   16
#define HD   64
#define MROWS (BB * SS)   // 8192

typedef __bf16 bf16x8 __attribute__((ext_vector_type(8)));
typedef float  f32x4  __attribute__((ext_vector_type(4)));

__device__ __forceinline__ unsigned short f2bf(float f) {
  union { float f; uint32_t u; } v; v.f = f;
  uint32_t u = v.u;
  uint32_t r = (u + 0x7fffu + ((u >> 16) & 1u)) >> 16;
  return (unsigned short)r;
}

#define GLOAD_LDS16(gsrc, ldst)                                                   \
  __builtin_amdgcn_global_load_lds(                                               \
      (const __attribute__((address_space(1))) void*)(gsrc),                      \
      (__attribute__((address_space(3))) void*)(ldst), 16, 0, 0)

// ---------------- conversion kernels ----------------

__global__ void cvt_x_kernel(const float* __restrict__ in,
                             unsigned short* __restrict__ out, int n4) {
  int i = blockIdx.x * blockDim.x + threadIdx.x;
  int stride = gridDim.x * blockDim.x;
  for (; i < n4; i += stride) {
    float4 f = ((const float4*)in)[i];
    ushort4 o;
    o.x = f2bf(f.x); o.y = f2bf(f.y); o.z = f2bf(f.z); o.w = f2bf(f.w);
    ((ushort4*)out)[i] = o;
  }
}

// transpose-convert: out[n][k] = bf16(W[k][n]), per blockIdx.z matrix
__global__ void cvt_w_t_kernel(const float* __restrict__ w0,
                               const float* __restrict__ w1,
                               const float* __restrict__ w2,
                               const float* __restrict__ w3,
                               unsigned short* __restrict__ out) {
  __shared__ float tile[32][33];
  const float* src = (blockIdx.z == 0) ? w0 : (blockIdx.z == 1) ? w1
                   : (blockIdx.z == 2) ? w2 : w3;
  unsigned short* dst = out + (size_t)blockIdx.z * (DIN * DOUT);
  int kb = blockIdx.x * 32, nb = blockIdx.y * 32;
  tile[threadIdx.y][threadIdx.x] = src[(size_t)(kb + threadIdx.y) * DOUT + nb + threadIdx.x];
  __syncthreads();
  dst[(size_t)(nb + threadIdx.y) * DIN + kb + threadIdx.x] = f2bf(tile[threadIdx.x][threadIdx.y]);
}

// ---------------- GEMM core: 128x128 tile, 4 waves, global_load_lds (m97) ----
// A: row-major [.,1024] bf16 (pre-offset to tile row 0)
// BT: row-major [.,1024] bf16 = B transposed (pre-offset to tile col 0)
__device__ __forceinline__ void gemm_core(const unsigned short* __restrict__ A,
                                          const unsigned short* __restrict__ BT,
                                          f32x4 (&acc)[4][4]) {
  const int tid  = threadIdx.x;
  const int lane = tid & 63;
  const int wave = tid >> 6;
  const int wm = (wave >> 1) * 64, wn = (wave & 1) * 64;
  const int g = lane >> 4, c = lane & 15;

  __shared__ __align__(16) unsigned short As[128 * 32];
  __shared__ __align__(16) unsigned short Bs[128 * 32];

#pragma unroll
  for (int mi = 0; mi < 4; mi++)
#pragma unroll
    for (int ni = 0; ni < 4; ni++)
      acc[mi][ni] = (f32x4){0.f, 0.f, 0.f, 0.f};

  // staging geometry: call j covers LDS rows [(j*4+wave)*16, +16), 64 lanes x 16B
  const int rj0 = (0 * 4 + wave) * 16 + (lane >> 2);
  const int rj1 = (1 * 4 + wave) * 16 + (lane >> 2);
  const int gcol = (lane & 3) * 8;
  const unsigned short* Ag0 = A + (size_t)rj0 * 1024 + gcol;
  const unsigned short* Ag1 = A + (size_t)rj1 * 1024 + gcol;
  const unsigned short* Bg0 = BT + (size_t)rj0 * 1024 + gcol;
  const unsigned short* Bg1 = BT + (size_t)rj1 * 1024 + gcol;
  unsigned short* As0 = &As[(0 * 4 + wave) * 512 + lane * 8];
  unsigned short* As1 = &As[(1 * 4 + wave) * 512 + lane * 8];
  unsigned short* Bs0 = &Bs[(0 * 4 + wave) * 512 + lane * 8];
  unsigned short* Bs1 = &Bs[(1 * 4 + wave) * 512 + lane * 8];

  for (int k0 = 0; k0 < 1024; k0 += 32) {
    __syncthreads();   // previous iteration's readers done
    GLOAD_LDS16(Ag0 + k0, As0);
    GLOAD_LDS16(Ag1 + k0, As1);
    GLOAD_LDS16(Bg0 + k0, Bs0);
    GLOAD_LDS16(Bg1 + k0, Bs1);
    __syncthreads();   // compiler drains vmcnt before s_barrier
    bf16x8 a[4], b[4];
#pragma unroll
    for (int mi = 0; mi < 4; mi++)
      a[mi] = *(const bf16x8*)&As[(wm + mi * 16 + c) * 32 + g * 8];
#pragma unroll
    for (int ni = 0; ni < 4; ni++)
      b[ni] = *(const bf16x8*)&Bs[(wn + ni * 16 + c) * 32 + g * 8];
#pragma unroll
    for (int mi = 0; mi < 4; mi++)
#pragma unroll
      for (int ni = 0; ni < 4; ni++)
        acc[mi][ni] = __builtin_amdgcn_mfma_f32_16x16x32_bf16(a[mi], b[ni], acc[mi][ni], 0, 0, 0);
  }
}

// QKV projection. z=0: Q (scaled 1/8) -> [b][h][s][hd]; z=1: K -> [b][h][s][hd];
// z=2: V -> transposed [b][h][hd][s]
__global__ __launch_bounds__(256) void gemm_qkv_kernel(
    const unsigned short* __restrict__ xb, const unsigned short* __restrict__ wt,
    unsigned short* __restrict__ qs, unsigned short* __restrict__ kbuf,
    unsigned short* __restrict__ vt) {
  const int nT = blockIdx.x, mT = blockIdx.y, z = blockIdx.z;
  f32x4 acc[4][4];
  gemm_core(xb + (size_t)mT * 128 * 1024,
            wt + (size_t)z * (DIN * DOUT) + (size_t)nT * 128 * 1024, acc);

  const int tid = threadIdx.x, lane = tid & 63, wave = tid >> 6;
  const int wm = (wave >> 1) * 64, wn = (wave & 1) * 64;
  const int g = lane >> 4, c = lane & 15;
  const float scale = (z == 0) ? 0.125f : 1.0f;
  unsigned short* dstQK = (z == 0) ? qs : kbuf;
#pragma unroll
  for (int mi = 0; mi < 4; mi++)
#pragma unroll
    for (int ni = 0; ni < 4; ni++) {
      int n = nT * 128 + wn + ni * 16 + c;
      int h = n >> 6, hd = n & 63;
#pragma unroll
      for (int jj = 0; jj < 4; jj++) {
        int m = mT * 128 + wm + mi * 16 + g * 4 + jj;
        int b = m >> 11, s = m & 2047;
        unsigned short val = f2bf(acc[mi][ni][jj] * scale);
        if (z < 2)
          dstQK[(((size_t)(b * NH + h)) * SS + s) * HD + hd] = val;
        else
          vt[(((size_t)(b * NH + h)) * HD + hd) * SS + s] = val;
      }
    }
}

// Output projection: out = ctx @ Wp + bp (fp32 out)
__global__ __launch_bounds__(256) void gemm_out_kernel(
    const unsigned short* __restrict__ ctx, const unsigned short* __restrict__ wtp,
    const float* __restrict__ bp, float* __restrict__ out) {
  const int nT = blockIdx.x, mT = blockIdx.y;
  f32x4 acc[4][4];
  gemm_core(ctx + (size_t)mT * 128 * 1024, wtp + (size_t)nT * 128 * 1024, acc);

  const int tid = threadIdx.x, lane = tid & 63, wave = tid >> 6;
  const int wm = (wave >> 1) * 64, wn = (wave & 1) * 64;
  const int g = lane >> 4, c = lane & 15;
#pragma unroll
  for (int mi = 0; mi < 4; mi++)
#pragma unroll
    for (int ni = 0; ni < 4; ni++) {
      int n = nT * 128 + wn + ni * 16 + c;
      float bias = bp[n];
#pragma unroll
      for (int jj = 0; jj < 4; jj++) {
        int m = mT * 128 + wm + mi * 16 + g * 4 + jj;
        out[(size_t)m * DOUT + n] = acc[mi][ni][jj] + bias;
      }
    }
}

// ---------------- flash attention ----------------
// grid: (S/128, H, B); block: 256 threads = 4 waves; wave w owns q rows
// [qt*128 + w*32, +32). KV tile = 64. K/V/P LDS XOR-swizzled (chunk ^= row&7).
__global__ __launch_bounds__(256) void attn_kernel(
    const unsigned short* __restrict__ qs, const unsigned short* __restrict__ kbuf,
    const unsigned short* __restrict__ vt, unsigned short* __restrict__ ctx) {
  const int qt = blockIdx.x, h = blockIdx.y, b = blockIdx.z;
  const int tid = threadIdx.x, lane = tid & 63, w = tid >> 6;
  const int g = lane >> 4, c = lane & 15;
  const size_t bh = (size_t)(b * NH + h);
  const unsigned short* Q = qs + bh * SS * HD;
  const unsigned short* K = kbuf + bh * SS * HD;
  const unsigned short* V = vt + bh * HD * SS;   // [hd][s]
  const int q0b = qt * 128;
  const int q0w = q0b + w * 32;

  // Q fragments: 2 m-frags x 2 k-halves, in registers
  bf16x8 aq[2][2];
#pragma unroll
  for (int mi = 0; mi < 2; mi++)
#pragma unroll
    for (int kk = 0; kk < 2; kk++)
      aq[mi][kk] = *(const bf16x8*)&Q[(size_t)(q0w + mi * 16 + c) * HD + kk * 32 + g * 8];

  float m_run[2][4], l_run[2][4];
  f32x4 acc[2][4];
#pragma unroll
  for (int mi = 0; mi < 2; mi++) {
#pragma unroll
    for (int jj = 0; jj < 4; jj++) { m_run[mi][jj] = -3.0e38f; l_run[mi][jj] = 0.f; }
#pragma unroll
    for (int nh = 0; nh < 4; nh++) acc[mi][nh] = (f32x4){0.f, 0.f, 0.f, 0.f};
  }

  // swizzled LDS: elem(row, col) = row*64 + ((col>>3 ^ (row&7)))*8 + (col&7)
  __shared__ __align__(16) unsigned short Klds[64 * 64];
  __shared__ __align__(16) unsigned short Vlds[64 * 64];   // [hd][kv]
  __shared__ __align__(16) unsigned short Plds[4][16 * 64];

  const int sr = tid >> 2;           // staging row 0..63
  const int ch0 = (tid & 3) * 2;     // first of two 8-elem chunks
  const int kw0 = sr * 64 + ((ch0 ^ (sr & 7)) * 8);
  const int kw1 = sr * 64 + (((ch0 + 1) ^ (sr & 7)) * 8);
  const unsigned short* Kg = K + (size_t)sr * HD + ch0 * 8;
  const unsigned short* Vg = V + (size_t)sr * SS + ch0 * 8;

  const int nt = 2 * qt + 2;

  // prefetch tile 0
  uint4 pk0 = *(const uint4*)(Kg);
  uint4 pk1 = *(const uint4*)(Kg + 8);
  uint4 pv0 = *(const uint4*)(Vg);
  uint4 pv1 = *(const uint4*)(Vg + 8);

  for (int t = 0; t < nt; ++t) {
    __syncthreads();                 // all waves done reading previous tile
    *(uint4*)&Klds[kw0] = pk0;
    *(uint4*)&Klds[kw1] = pk1;
    *(uint4*)&Vlds[kw0] = pv0;
    *(uint4*)&Vlds[kw1] = pv1;
    __syncthreads();
    if (t + 1 < nt) {                // prefetch next tile; hides under compute
      pk0 = *(const uint4*)(Kg + (size_t)(t + 1) * 64 * HD);
      pk1 = *(const uint4*)(Kg + (size_t)(t + 1) * 64 * HD + 8);
      pv0 = *(const uint4*)(Vg + (t + 1) * 64);
      pv1 = *(const uint4*)(Vg + (t + 1) * 64 + 8);
    }
    const int kv0 = t * 64;
    if (kv0 > q0w + 31) continue;    // tile fully above diagonal for this wave

    // S = Q K^T
    bf16x8 kf[4][2];
#pragma unroll
    for (int ni = 0; ni < 4; ni++)
#pragma unroll
      for (int kk = 0; kk < 2; kk++)
        kf[ni][kk] = *(const bf16x8*)&Klds[(ni * 16 + c) * 64 + (((kk * 4 + g) ^ (c & 7)) * 8)];
    f32x4 sv[2][4];
#pragma unroll
    for (int mi = 0; mi < 2; mi++)
#pragma unroll
      for (int ni = 0; ni < 4; ni++) {
        sv[mi][ni] = (f32x4){0.f, 0.f, 0.f, 0.f};
#pragma unroll
        for (int kk = 0; kk < 2; kk++)
          sv[mi][ni] = __builtin_amdgcn_mfma_f32_16x16x32_bf16(aq[mi][kk], kf[ni][kk], sv[mi][ni], 0, 0, 0);
      }

    if (kv0 + 63 > q0w) {            // causal mask only near the diagonal
#pragma unroll
      for (int mi = 0; mi < 2; mi++)
#pragma unroll
        for (int ni = 0; ni < 4; ni++)
#pragma unroll
          for (int jj = 0; jj < 4; jj++) {
            int kvg = kv0 + ni * 16 + c;
            int qg  = q0w + mi * 16 + g * 4 + jj;
            if (kvg > qg) sv[mi][ni][jj] = -3.0e38f;
          }
    }

    // online softmax per q row; p overwrites sv in place
    float alpha[2][4];
#pragma unroll
    for (int mi = 0; mi < 2; mi++)
#pragma unroll
      for (int jj = 0; jj < 4; jj++) {
        float mx = fmaxf(fmaxf(sv[mi][0][jj], sv[mi][1][jj]), fmaxf(sv[mi][2][jj], sv[mi][3][jj]));
#pragma unroll
        for (int d = 1; d < 16; d <<= 1) mx = fmaxf(mx, __shfl_xor(mx, d));
        float mnew = fmaxf(m_run[mi][jj], mx);
        alpha[mi][jj] = __expf(m_run[mi][jj] - mnew);
        m_run[mi][jj] = mnew;
        float rs = 0.f;
#pragma unroll
        for (int ni = 0; ni < 4; ni++) {
          float pv = __expf(sv[mi][ni][jj] - mnew);
          sv[mi][ni][jj] = pv;
          rs += pv;
        }
#pragma unroll
        for (int d = 1; d < 16; d <<= 1) rs += __shfl_xor(rs, d);
        l_run[mi][jj] = l_run[mi][jj] * alpha[mi][jj] + rs;
      }
#pragma unroll
    for (int mi = 0; mi < 2; mi++)
#pragma unroll
      for (int nh = 0; nh < 4; nh++)
#pragma unroll
        for (int jj = 0; jj < 4; jj++) acc[mi][nh][jj] *= alpha[mi][jj];

    // V fragments (shared across both m-frags)
    bf16x8 vb[4][2];
#pragma unroll
    for (int nh = 0; nh < 4; nh++)
#pragma unroll
      for (int kk = 0; kk < 2; kk++)
        vb[nh][kk] = *(const bf16x8*)&Vlds[(nh * 16 + c) * 64 + (((kk * 4 + g) ^ (c & 7)) * 8)];

    // per m-frag: transpose P through swizzled per-wave LDS, then PV
#pragma unroll
    for (int mi = 0; mi < 2; mi++) {
#pragma unroll
      for (int ni = 0; ni < 4; ni++)
#pragma unroll
        for (int jj = 0; jj < 4; jj++) {
          int row = g * 4 + jj, col = ni * 16 + c;
          Plds[w][row * 64 + (((col >> 3) ^ (row & 7)) * 8) + (col & 7)] = f2bf(sv[mi][ni][jj]);
        }
      bf16x8 pa[2];
#pragma unroll
      for (int kk = 0; kk < 2; kk++)
        pa[kk] = *(const bf16x8*)&Plds[w][c * 64 + (((kk * 4 + g) ^ (c & 7)) * 8)];
#pragma unroll
      for (int nh = 0; nh < 4; nh++)
#pragma unroll
        for (int kk = 0; kk < 2; kk++)
          acc[mi][nh] = __builtin_amdgcn_mfma_f32_16x16x32_bf16(pa[kk], vb[nh][kk], acc[mi][nh], 0, 0, 0);
    }
  }

  // epilogue: ctx2d[b*S+s][h*64+hd] = acc / l
#pragma unroll
  for (int mi = 0; mi < 2; mi++)
#pragma unroll
    for (int nh = 0; nh < 4; nh++)
#pragma unroll
      for (int jj = 0; jj < 4; jj++) {
        int m = q0w + mi * 16 + g * 4 + jj;
        int col = h * HD + nh * 16 + c;
        size_t row = (size_t)b * SS + m;
        ctx[row * DOUT + col] = f2bf(acc[mi][nh][jj] / l_run[mi][jj]);
      }
}

// ---------------- launch ----------------

extern "C" void kernel_launch(void* const* d_in, const int* in_sizes, int n_in,
                              void* d_out, int out_size, void* d_ws, size_t ws_size,
                              hipStream_t stream) {
  const float* x  = (const float*)d_in[0];
  const float* Wq = (const float*)d_in[1];
  const float* Wk = (const float*)d_in[2];
  const float* Wv = (const float*)d_in[3];
  const float* Wp = (const float*)d_in[4];
  const float* bp = (const float*)d_in[5];
  float* out = (float*)d_out;

  unsigned short* ws = (unsigned short*)d_ws;
  unsigned short* xb = ws;                      // 8388608 elems (x bf16; later reused as ctx)
  unsigned short* wt = xb + (size_t)MROWS * DIN;       // 4 * 1048576 (Wq^T,Wk^T,Wv^T,Wp^T)
  unsigned short* qs = wt + (size_t)4 * DIN * DOUT;    // 8388608 (Q scaled, [b][h][s][hd])
  unsigned short* kb = qs + (size_t)MROWS * DOUT;      // 8388608 ([b][h][s][hd])
  unsigned short* vt = kb + (size_t)MROWS * DOUT;      // 8388608 ([b][h][hd][s])
  unsigned short* ctx = xb;                            // alias: x dead after projections

  cvt_x_kernel<<<4096, 256, 0, stream>>>(x, xb, (MROWS * DIN) / 4);
  cvt_w_t_kernel<<<dim3(32, 32, 4), dim3(32, 32), 0, stream>>>(Wq, Wk, Wv, Wp, wt);
  gemm_qkv_kernel<<<dim3(8, 64, 3), 256, 0, stream>>>(xb, wt, qs, kb, vt);
  attn_kernel<<<dim3(SS / 128, NH, BB), 256, 0, stream>>>(qs, kb, vt, ctx);
  gemm_out_kernel<<<dim3(8, 64), 256, 0, stream>>>(ctx, wt + (size_t)3 * DIN * DOUT, bp, out);
}